// Round 1
// baseline (365.746 us; speedup 1.0000x reference)
//
#include <hip/hip_runtime.h>
#include <math.h>

#define BATCH 2048
#define NW    16384   // neurons = 128*128
#define FEAT  256
#define SOMC  128     // cols
#define BM    128
#define BN    128
#define BK    32
#define LDK   36      // padded LDS stride in floats (144B, 16B-aligned, banks spread)

// d_ws layout:
//   [0, BATCH)            float xnorm
//   [BATCH, BATCH+NW)     float wnorm
//   then (8-aligned)      BATCH x u64 packed (dist_bits<<32 | neuron_idx)

__global__ __launch_bounds__(256) void som_prep(const float* __restrict__ x,
                                                const float* __restrict__ w,
                                                float* __restrict__ xn,
                                                float* __restrict__ wn,
                                                unsigned long long* __restrict__ bmu) {
    const int wave = threadIdx.x >> 6;
    const int lane = threadIdx.x & 63;
    const int row  = blockIdx.x * 4 + wave;   // 0 .. BATCH+NW-1  (18432 rows total)
    const float* src = (row < BATCH) ? (x + (size_t)row * FEAT)
                                     : (w + (size_t)(row - BATCH) * FEAT);
    float4 v = ((const float4*)src)[lane];    // 64 lanes * 4 floats = 256
    float s = v.x * v.x + v.y * v.y + v.z * v.z + v.w * v.w;
    #pragma unroll
    for (int off = 32; off >= 1; off >>= 1)
        s += __shfl_xor(s, off, 64);
    if (lane == 0) {
        if (row < BATCH) { xn[row] = s; bmu[row] = 0xFFFFFFFFFFFFFFFFULL; }
        else             { wn[row - BATCH] = s; }
    }
}

__global__ __launch_bounds__(256) void som_main(const float* __restrict__ x,
                                                const float* __restrict__ w,
                                                const float* __restrict__ xn,
                                                const float* __restrict__ wn,
                                                float* __restrict__ out,
                                                unsigned long long* __restrict__ bmu) {
    __shared__ float xs[BM][LDK];
    __shared__ float wsh[BN][LDK];

    const int t  = threadIdx.x;
    const int tx = t & 15;        // 0..15 -> col group
    const int ty = t >> 4;        // 0..15 -> row group
    const int brow = blockIdx.y * BM;
    const int bcol = blockIdx.x * BN;

    float acc[8][8];
    #pragma unroll
    for (int i = 0; i < 8; ++i)
        #pragma unroll
        for (int j = 0; j < 8; ++j) acc[i][j] = 0.0f;

    for (int k0 = 0; k0 < FEAT; k0 += BK) {
        // ---- stage: each thread loads 4 float4 of x-tile and 4 of w-tile ----
        #pragma unroll
        for (int r = 0; r < 4; ++r) {
            const int flat = (t + r * 256) * 4;   // 0..4095 floats in 128x32 tile
            const int row  = flat >> 5;           // /32
            const int col  = flat & 31;
            float4 xv = *(const float4*)&x[(size_t)(brow + row) * FEAT + k0 + col];
            float4 wv = *(const float4*)&w[(size_t)(bcol + row) * FEAT + k0 + col];
            *(float4*)&xs[row][col]  = xv;
            *(float4*)&wsh[row][col] = wv;
        }
        __syncthreads();

        // ---- compute: 8 k-quads of BK=32 ----
        #pragma unroll
        for (int kq = 0; kq < BK / 4; ++kq) {
            float4 a[8], b[8];
            #pragma unroll
            for (int i = 0; i < 8; ++i)
                a[i] = *(const float4*)&xs[ty + 16 * i][kq * 4];
            #pragma unroll
            for (int j = 0; j < 8; ++j)
                b[j] = *(const float4*)&wsh[tx + 16 * j][kq * 4];
            #pragma unroll
            for (int i = 0; i < 8; ++i)
                #pragma unroll
                for (int j = 0; j < 8; ++j) {
                    acc[i][j] += a[i].x * b[j].x;
                    acc[i][j] += a[i].y * b[j].y;
                    acc[i][j] += a[i].z * b[j].z;
                    acc[i][j] += a[i].w * b[j].w;
                }
        }
        __syncthreads();
    }

    // ---- epilogue: d = sqrt(max(xn + wn - 2*dot, 0)), store + argmin ----
    #pragma unroll
    for (int i = 0; i < 8; ++i) {
        const int rg = brow + ty + 16 * i;
        const float xnv = xn[rg];
        unsigned long long best = 0xFFFFFFFFFFFFFFFFULL;
        #pragma unroll
        for (int j = 0; j < 8; ++j) {
            const int cg = bcol + tx + 16 * j;
            float d2 = xnv + wn[cg] - 2.0f * acc[i][j];
            d2 = fmaxf(d2, 0.0f);
            float d = sqrtf(d2);
            out[(size_t)rg * NW + cg] = d;
            unsigned long long p =
                ((unsigned long long)__float_as_uint(d) << 32) | (unsigned int)cg;
            if (p < best) best = p;
        }
        // reduce across the 16 lanes (tx=0..15) holding the same row set
        #pragma unroll
        for (int off = 8; off >= 1; off >>= 1) {
            unsigned long long o = __shfl_xor(best, off, 64);
            if (o < best) best = o;
        }
        if (tx == 0) atomicMin(&bmu[rg], best);
    }
}

__global__ __launch_bounds__(256) void som_bmu_write(const unsigned long long* __restrict__ bmu,
                                                     float* __restrict__ outb) {
    const int i = blockIdx.x * blockDim.x + threadIdx.x;
    if (i >= BATCH) return;
    const unsigned int idx = (unsigned int)(bmu[i] & 0xFFFFFFFFu);
    outb[(size_t)i * 2 + 0] = (float)(idx >> 7);     // row = idx / 128
    outb[(size_t)i * 2 + 1] = (float)(idx & (SOMC - 1)); // col = idx % 128
}

extern "C" void kernel_launch(void* const* d_in, const int* in_sizes, int n_in,
                              void* d_out, int out_size, void* d_ws, size_t ws_size,
                              hipStream_t stream) {
    const float* x = (const float*)d_in[0];
    const float* w = (const float*)d_in[1];
    float* out = (float*)d_out;

    float* xn = (float*)d_ws;
    float* wn = xn + BATCH;
    unsigned long long* bmu =
        (unsigned long long*)((char*)d_ws + (size_t)(BATCH + NW) * sizeof(float)); // 73728, 8-aligned

    // norms + bmu init: one wave per row, 4 waves/block, 18432 rows
    som_prep<<<(BATCH + NW) / 4, 256, 0, stream>>>(x, w, xn, wn, bmu);

    // main GEMM-like distance kernel
    dim3 grid(NW / BN, BATCH / BM);   // 128 x 16 = 2048 blocks
    som_main<<<grid, 256, 0, stream>>>(x, w, xn, wn, out, bmu);

    // unpack BMUs as floats at the tail of d_out
    float* outb = out + (size_t)BATCH * NW;
    som_bmu_write<<<(BATCH + 255) / 256, 256, 0, stream>>>(bmu, outb);
}

// Round 2
// 142.055 us; speedup vs baseline: 2.5747x; 2.5747x over previous
//
#include <hip/hip_runtime.h>
#include <math.h>

#define BATCH 2048
#define NW    16384   // neurons = 128*128
#define FEAT  256
#define SOMC  128
#define BM    128
#define BN    128
#define KTILES 8      // 8 K-tiles of 32 original k each
#define SPLITK 512    // bf16 per row after split: per K-tile [32 hi | 32 lo]

typedef __attribute__((ext_vector_type(8))) short short8v;   // 8 bf16 = 4 VGPR
typedef __attribute__((ext_vector_type(4))) float float4v;

// ---- ws layout (new path) ----
// xn   : 0                      2048 f32      (8 KB)
// wn   : 8192                   16384 f32     (64 KB)
// bmu  : 73728                  2048 u64      (16 KB)
// xsp  : 90112                  2048*512 bf16 (2 MB)
// wsp  : 2187264                16384*512 bf16(16 MB)
#define WS_NEEDED 18964480ull

static __device__ __forceinline__ unsigned short f2bf(float f) {
    unsigned u = __float_as_uint(f);
    unsigned r = u + 0x7FFFu + ((u >> 16) & 1u);  // RNE
    return (unsigned short)(r >> 16);
}

// ---------------- prep: norms + bmu init + hi/lo bf16 split ----------------
__global__ __launch_bounds__(256) void som_prep_split(const float* __restrict__ x,
                                                      const float* __restrict__ w,
                                                      float* __restrict__ xn,
                                                      float* __restrict__ wn,
                                                      unsigned long long* __restrict__ bmu,
                                                      unsigned short* __restrict__ xsp,
                                                      unsigned short* __restrict__ wsp) {
    const int wv = threadIdx.x >> 6;
    const int lane = threadIdx.x & 63;
    const int row = blockIdx.x * 4 + wv;            // 0 .. 18431
    const bool isx = row < BATCH;
    const float* src = isx ? x + (size_t)row * FEAT
                           : w + (size_t)(row - BATCH) * FEAT;
    float4 v = ((const float4*)src)[lane];          // k = lane*4 .. +3
    float s = v.x * v.x + v.y * v.y + v.z * v.z + v.w * v.w;
    #pragma unroll
    for (int o = 32; o; o >>= 1) s += __shfl_xor(s, o, 64);

    float fx[4] = {v.x, v.y, v.z, v.w};
    unsigned short h[4], l[4];
    #pragma unroll
    for (int i = 0; i < 4; ++i) {
        h[i] = f2bf(fx[i]);
        float hf = __uint_as_float((unsigned)h[i] << 16);
        l[i] = f2bf(fx[i] - hf);
    }
    unsigned short* dst = isx ? xsp + (size_t)row * SPLITK
                              : wsp + (size_t)(row - BATCH) * SPLITK;
    const int k = lane * 4;
    const int base = (k >> 5) * 64 + (k & 31);      // K-tile slot: [32 hi | 32 lo]
    *(ushort4*)(dst + base)      = make_ushort4(h[0], h[1], h[2], h[3]);
    *(ushort4*)(dst + base + 32) = make_ushort4(l[0], l[1], l[2], l[3]);

    if (lane == 0) {
        if (isx) { xn[row] = s; bmu[row] = 0xFFFFFFFFFFFFFFFFULL; }
        else     { wn[row - BATCH] = s; }
    }
}

// ---------------- main MFMA kernel ----------------
__global__ __launch_bounds__(256, 2) void som_mfma(const unsigned short* __restrict__ xsp,
                                                   const unsigned short* __restrict__ wsp,
                                                   const float* __restrict__ xn,
                                                   const float* __restrict__ wn,
                                                   float* __restrict__ out,
                                                   unsigned long long* __restrict__ bmu) {
    // LDS tile: 128 rows x 128 bytes (per K-tile: 32 hi + 32 lo bf16 per row)
    __shared__ __align__(16) char xsb[128 * 128];
    __shared__ __align__(16) char wsb[128 * 128];

    const int t = threadIdx.x;
    const int brow = blockIdx.y * BM;
    const int bcol = blockIdx.x * BN;
    const int lane = t & 63, wv = t >> 6;
    const int wrow = (wv >> 1) * 64;   // wave tile origin in block
    const int wcol = (wv & 1) * 64;
    const int s = lane & 15, q = lane >> 4;

    float4v acc[4][4];
    #pragma unroll
    for (int m = 0; m < 4; ++m)
        #pragma unroll
        for (int n = 0; n < 4; ++n)
            acc[m][n] = (float4v){0.f, 0.f, 0.f, 0.f};

    for (int kt = 0; kt < KTILES; ++kt) {
        // ---- stage: 1024 16B-chunks per tile, 4 per thread; XOR-swizzled dest ----
        #pragma unroll
        for (int i = 0; i < 4; ++i) {
            const int ch = t + i * 256;
            const int r = ch >> 3, c = ch & 7;
            const int dst = r * 128 + ((c * 16) ^ ((r & 7) << 4));
            const uint4 xv = *(const uint4*)(xsp + (size_t)(brow + r) * SPLITK + kt * 64 + c * 8);
            const uint4 wvv = *(const uint4*)(wsp + (size_t)(bcol + r) * SPLITK + kt * 64 + c * 8);
            *(uint4*)(xsb + dst) = xv;
            *(uint4*)(wsb + dst) = wvv;
        }
        __syncthreads();

        // ---- fragments (same swizzle on read) ----
        short8v ah[4], al[4], bh[4], bl[4];
        #pragma unroll
        for (int m = 0; m < 4; ++m) {
            const int r = wrow + m * 16 + s;
            const int sw = (r & 7) << 4;
            ah[m] = *(const short8v*)(xsb + r * 128 + ((q * 16) ^ sw));
            al[m] = *(const short8v*)(xsb + r * 128 + ((64 + q * 16) ^ sw));
        }
        #pragma unroll
        for (int n = 0; n < 4; ++n) {
            const int r = wcol + n * 16 + s;
            const int sw = (r & 7) << 4;
            bh[n] = *(const short8v*)(wsb + r * 128 + ((q * 16) ^ sw));
            bl[n] = *(const short8v*)(wsb + r * 128 + ((64 + q * 16) ^ sw));
        }

        // ---- 4-pass MFMA: (xh+xl)·(wh+wl) ----
        #pragma unroll
        for (int m = 0; m < 4; ++m)
            #pragma unroll
            for (int n = 0; n < 4; ++n) {
                acc[m][n] = __builtin_amdgcn_mfma_f32_16x16x32_bf16(ah[m], bh[n], acc[m][n], 0, 0, 0);
                acc[m][n] = __builtin_amdgcn_mfma_f32_16x16x32_bf16(ah[m], bl[n], acc[m][n], 0, 0, 0);
                acc[m][n] = __builtin_amdgcn_mfma_f32_16x16x32_bf16(al[m], bh[n], acc[m][n], 0, 0, 0);
                acc[m][n] = __builtin_amdgcn_mfma_f32_16x16x32_bf16(al[m], bl[n], acc[m][n], 0, 0, 0);
            }
        __syncthreads();
    }

    // ---- epilogue: d = sqrt(max(xn+wn-2*dot,0)), store + argmin ----
    // C/D mapping (m89-verified): col = lane&15, row = (lane>>4)*4 + reg
    #pragma unroll
    for (int m = 0; m < 4; ++m) {
        #pragma unroll
        for (int reg = 0; reg < 4; ++reg) {
            const int rg = brow + wrow + m * 16 + q * 4 + reg;
            const float xv = xn[rg];
            unsigned long long best = 0xFFFFFFFFFFFFFFFFULL;
            #pragma unroll
            for (int n = 0; n < 4; ++n) {
                const int cg = bcol + wcol + n * 16 + s;
                float d2 = xv + wn[cg] - 2.0f * acc[m][n][reg];
                d2 = fmaxf(d2, 0.0f);
                float d = sqrtf(d2);
                out[(size_t)rg * NW + cg] = d;
                unsigned long long p =
                    ((unsigned long long)__float_as_uint(d) << 32) | (unsigned)cg;
                if (p < best) best = p;
            }
            #pragma unroll
            for (int o = 8; o; o >>= 1) {
                unsigned long long ob = __shfl_xor(best, o, 64);
                if (ob < best) best = ob;
            }
            if (s == 0) atomicMin(&bmu[rg], best);
        }
    }
}

// ---------------- fallback f32 path (round-1, known-passing) ----------------
#define BK  32
#define LDK 36

__global__ __launch_bounds__(256) void som_prep(const float* __restrict__ x,
                                                const float* __restrict__ w,
                                                float* __restrict__ xn,
                                                float* __restrict__ wn,
                                                unsigned long long* __restrict__ bmu) {
    const int wave = threadIdx.x >> 6;
    const int lane = threadIdx.x & 63;
    const int row  = blockIdx.x * 4 + wave;
    const float* src = (row < BATCH) ? (x + (size_t)row * FEAT)
                                     : (w + (size_t)(row - BATCH) * FEAT);
    float4 v = ((const float4*)src)[lane];
    float s = v.x * v.x + v.y * v.y + v.z * v.z + v.w * v.w;
    #pragma unroll
    for (int off = 32; off >= 1; off >>= 1) s += __shfl_xor(s, off, 64);
    if (lane == 0) {
        if (row < BATCH) { xn[row] = s; bmu[row] = 0xFFFFFFFFFFFFFFFFULL; }
        else             { wn[row - BATCH] = s; }
    }
}

__global__ __launch_bounds__(256) void som_f32main(const float* __restrict__ x,
                                                   const float* __restrict__ w,
                                                   const float* __restrict__ xn,
                                                   const float* __restrict__ wn,
                                                   float* __restrict__ out,
                                                   unsigned long long* __restrict__ bmu) {
    __shared__ float xs[BM][LDK];
    __shared__ float wsh[BN][LDK];
    const int t  = threadIdx.x;
    const int tx = t & 15;
    const int ty = t >> 4;
    const int brow = blockIdx.y * BM;
    const int bcol = blockIdx.x * BN;
    float acc[8][8];
    #pragma unroll
    for (int i = 0; i < 8; ++i)
        #pragma unroll
        for (int j = 0; j < 8; ++j) acc[i][j] = 0.0f;
    for (int k0 = 0; k0 < FEAT; k0 += BK) {
        #pragma unroll
        for (int r = 0; r < 4; ++r) {
            const int flat = (t + r * 256) * 4;
            const int row  = flat >> 5;
            const int col  = flat & 31;
            float4 xv = *(const float4*)&x[(size_t)(brow + row) * FEAT + k0 + col];
            float4 wv = *(const float4*)&w[(size_t)(bcol + row) * FEAT + k0 + col];
            *(float4*)&xs[row][col]  = xv;
            *(float4*)&wsh[row][col] = wv;
        }
        __syncthreads();
        #pragma unroll
        for (int kq = 0; kq < BK / 4; ++kq) {
            float4 a[8], b[8];
            #pragma unroll
            for (int i = 0; i < 8; ++i) a[i] = *(const float4*)&xs[ty + 16 * i][kq * 4];
            #pragma unroll
            for (int j = 0; j < 8; ++j) b[j] = *(const float4*)&wsh[tx + 16 * j][kq * 4];
            #pragma unroll
            for (int i = 0; i < 8; ++i)
                #pragma unroll
                for (int j = 0; j < 8; ++j) {
                    acc[i][j] += a[i].x * b[j].x;
                    acc[i][j] += a[i].y * b[j].y;
                    acc[i][j] += a[i].z * b[j].z;
                    acc[i][j] += a[i].w * b[j].w;
                }
        }
        __syncthreads();
    }
    #pragma unroll
    for (int i = 0; i < 8; ++i) {
        const int rg = brow + ty + 16 * i;
        const float xnv = xn[rg];
        unsigned long long best = 0xFFFFFFFFFFFFFFFFULL;
        #pragma unroll
        for (int j = 0; j < 8; ++j) {
            const int cg = bcol + tx + 16 * j;
            float d2 = xnv + wn[cg] - 2.0f * acc[i][j];
            d2 = fmaxf(d2, 0.0f);
            float d = sqrtf(d2);
            out[(size_t)rg * NW + cg] = d;
            unsigned long long p =
                ((unsigned long long)__float_as_uint(d) << 32) | (unsigned int)cg;
            if (p < best) best = p;
        }
        #pragma unroll
        for (int off = 8; off >= 1; off >>= 1) {
            unsigned long long o = __shfl_xor(best, off, 64);
            if (o < best) best = o;
        }
        if (tx == 0) atomicMin(&bmu[rg], best);
    }
}

__global__ __launch_bounds__(256) void som_bmu_write(const unsigned long long* __restrict__ bmu,
                                                     float* __restrict__ outb) {
    const int i = blockIdx.x * blockDim.x + threadIdx.x;
    if (i >= BATCH) return;
    const unsigned int idx = (unsigned int)(bmu[i] & 0xFFFFFFFFu);
    outb[(size_t)i * 2 + 0] = (float)(idx >> 7);
    outb[(size_t)i * 2 + 1] = (float)(idx & (SOMC - 1));
}

extern "C" void kernel_launch(void* const* d_in, const int* in_sizes, int n_in,
                              void* d_out, int out_size, void* d_ws, size_t ws_size,
                              hipStream_t stream) {
    const float* x = (const float*)d_in[0];
    const float* w = (const float*)d_in[1];
    float* out = (float*)d_out;

    float* xn = (float*)d_ws;
    float* wn = xn + BATCH;
    unsigned long long* bmu = (unsigned long long*)((char*)d_ws + 73728);
    float* outb = out + (size_t)BATCH * NW;

    if (ws_size >= WS_NEEDED) {
        unsigned short* xsp = (unsigned short*)((char*)d_ws + 90112);
        unsigned short* wsp = (unsigned short*)((char*)d_ws + 2187264);
        som_prep_split<<<(BATCH + NW) / 4, 256, 0, stream>>>(x, w, xn, wn, bmu, xsp, wsp);
        dim3 grid(NW / BN, BATCH / BM);   // 128 x 16
        som_mfma<<<grid, 256, 0, stream>>>(xsp, wsp, xn, wn, out, bmu);
    } else {
        som_prep<<<(BATCH + NW) / 4, 256, 0, stream>>>(x, w, xn, wn, bmu);
        dim3 grid(NW / BN, BATCH / BM);
        som_f32main<<<grid, 256, 0, stream>>>(x, w, xn, wn, out, bmu);
    }
    som_bmu_write<<<(BATCH + 255) / 256, 256, 0, stream>>>(bmu, outb);
}

// Round 3
// 121.563 us; speedup vs baseline: 3.0087x; 1.1686x over previous
//
#include <hip/hip_runtime.h>
#include <math.h>

#define BATCH 2048
#define NW    16384   // neurons = 128*128
#define FEAT  256
#define SOMC  128
#define BM    128
#define BN    128
#define KTILES 8      // 8 K-tiles of 64 bf16 (32 hi | 32 lo)
#define SPLITK 512    // bf16 per row after hi/lo split

typedef __attribute__((ext_vector_type(8))) short short8v;   // 8 bf16 = 4 VGPR
typedef __attribute__((ext_vector_type(4))) float float4v;

// ---- ws layout ----
// xn   : 0                      2048 f32
// wn   : 8192                   16384 f32
// bmu  : 73728                  2048 u64
// xsp  : 90112                  2048*512 bf16 (2 MB)
// wsp  : 2187264                16384*512 bf16 (16 MB)
#define WS_NEEDED 18964480ull

static __device__ __forceinline__ unsigned short f2bf(float f) {
    unsigned u = __float_as_uint(f);
    unsigned r = u + 0x7FFFu + ((u >> 16) & 1u);  // RNE
    return (unsigned short)(r >> 16);
}

static __device__ __forceinline__ void gload16(const void* g, void* l) {
    __builtin_amdgcn_global_load_lds(
        (const __attribute__((address_space(1))) unsigned int*)g,
        (__attribute__((address_space(3))) unsigned int*)l, 16, 0, 0);
}

// ---------------- prep: norms + bmu init + hi/lo bf16 split ----------------
__global__ __launch_bounds__(256) void som_prep_split(const float* __restrict__ x,
                                                      const float* __restrict__ w,
                                                      float* __restrict__ xn,
                                                      float* __restrict__ wn,
                                                      unsigned long long* __restrict__ bmu,
                                                      unsigned short* __restrict__ xsp,
                                                      unsigned short* __restrict__ wsp) {
    const int wv = threadIdx.x >> 6;
    const int lane = threadIdx.x & 63;
    const int row = blockIdx.x * 4 + wv;            // 0 .. 18431
    const bool isx = row < BATCH;
    const float* src = isx ? x + (size_t)row * FEAT
                           : w + (size_t)(row - BATCH) * FEAT;
    float4 v = ((const float4*)src)[lane];          // k = lane*4 .. +3
    float s = v.x * v.x + v.y * v.y + v.z * v.z + v.w * v.w;
    #pragma unroll
    for (int o = 32; o; o >>= 1) s += __shfl_xor(s, o, 64);

    float fx[4] = {v.x, v.y, v.z, v.w};
    unsigned short h[4], l[4];
    #pragma unroll
    for (int i = 0; i < 4; ++i) {
        h[i] = f2bf(fx[i]);
        float hf = __uint_as_float((unsigned)h[i] << 16);
        l[i] = f2bf(fx[i] - hf);
    }
    unsigned short* dst = isx ? xsp + (size_t)row * SPLITK
                              : wsp + (size_t)(row - BATCH) * SPLITK;
    const int k = lane * 4;
    const int base = (k >> 5) * 64 + (k & 31);      // K-tile slot: [32 hi | 32 lo]
    *(ushort4*)(dst + base)      = make_ushort4(h[0], h[1], h[2], h[3]);
    *(ushort4*)(dst + base + 32) = make_ushort4(l[0], l[1], l[2], l[3]);

    if (lane == 0) {
        if (isx) { xn[row] = s; bmu[row] = 0xFFFFFFFFFFFFFFFFULL; }
        else     { wn[row - BATCH] = s; }
    }
}

// ---------------- main MFMA kernel (m97-style: gload_lds + 2 barriers) ----------------
__global__ __launch_bounds__(256, 4) void som_mfma(const unsigned short* __restrict__ xsp,
                                                   const unsigned short* __restrict__ wsp,
                                                   const float* __restrict__ xn,
                                                   const float* __restrict__ wn,
                                                   float* __restrict__ out,
                                                   unsigned long long* __restrict__ bmu) {
    // LDS tiles: 128 rows x 128 B (one K-tile: 32 hi + 32 lo bf16 per row).
    // Written LINEARLY by global_load_lds; the XOR swizzle lives in the
    // pre-swizzled global source chunk (rule #21: source-perm == read-perm).
    __shared__ __align__(16) char xsb[128 * 128];
    __shared__ __align__(16) char wsb[128 * 128];

    const int t = threadIdx.x;
    const int brow = blockIdx.y * BM;
    const int bcol = blockIdx.x * BN;
    const int lane = t & 63, wv = t >> 6;
    const int wrow = (wv >> 1) * 64;   // wave tile origin in block
    const int wcol = (wv & 1) * 64;
    const int s = lane & 15, q = lane >> 4;

    // Staging: wave wv owns rows [wv*32, wv*32+32) of both tiles.
    // Each gload_lds: 64 lanes x 16 B = 8 rows. Lane covers row srow=(lane>>3),
    // swizzled chunk (lane&7)^(srow&7); since blocks of 8 rows are 8-aligned,
    // (r&7) == (lane>>3) for every j.
    const int srow   = wv * 32 + (lane >> 3);
    const int schunk = (lane & 7) ^ (lane >> 3);
    const unsigned short* gx = xsp + (size_t)(brow + srow) * SPLITK + schunk * 8;
    const unsigned short* gw = wsp + (size_t)(bcol + srow) * SPLITK + schunk * 8;
    char* lx = xsb + (wv * 32) * 128;   // wave-uniform LDS bases
    char* lw = wsb + (wv * 32) * 128;

    float4v acc[4][4];
    #pragma unroll
    for (int m = 0; m < 4; ++m)
        #pragma unroll
        for (int n = 0; n < 4; ++n)
            acc[m][n] = (float4v){0.f, 0.f, 0.f, 0.f};

    #pragma unroll
    for (int kt = 0; kt < KTILES; ++kt) {
        // ---- stage via async global->LDS (4 x-rows-of-8 + 4 w-rows-of-8 per wave) ----
        #pragma unroll
        for (int j = 0; j < 4; ++j) {
            gload16(gx + (size_t)j * 8 * SPLITK + kt * 64, lx + j * 1024);
            gload16(gw + (size_t)j * 8 * SPLITK + kt * 64, lw + j * 1024);
        }
        __syncthreads();   // drains vmcnt -> LDS tile complete for all waves

        // ---- fragments (XOR swizzle on read) ----
        short8v ah[4], al[4], bh[4], bl[4];
        #pragma unroll
        for (int m = 0; m < 4; ++m) {
            const int r = wrow + m * 16 + s;
            const int sw = (r & 7) << 4;
            ah[m] = *(const short8v*)(xsb + r * 128 + ((q * 16) ^ sw));
            al[m] = *(const short8v*)(xsb + r * 128 + ((64 + q * 16) ^ sw));
        }
        #pragma unroll
        for (int n = 0; n < 4; ++n) {
            const int r = wcol + n * 16 + s;
            const int sw = (r & 7) << 4;
            bh[n] = *(const short8v*)(wsb + r * 128 + ((q * 16) ^ sw));
            bl[n] = *(const short8v*)(wsb + r * 128 + ((64 + q * 16) ^ sw));
        }

        // ---- 4-pass MFMA: (xh+xl)·(wh+wl) ----
        #pragma unroll
        for (int m = 0; m < 4; ++m)
            #pragma unroll
            for (int n = 0; n < 4; ++n) {
                acc[m][n] = __builtin_amdgcn_mfma_f32_16x16x32_bf16(ah[m], bh[n], acc[m][n], 0, 0, 0);
                acc[m][n] = __builtin_amdgcn_mfma_f32_16x16x32_bf16(ah[m], bl[n], acc[m][n], 0, 0, 0);
                acc[m][n] = __builtin_amdgcn_mfma_f32_16x16x32_bf16(al[m], bh[n], acc[m][n], 0, 0, 0);
                acc[m][n] = __builtin_amdgcn_mfma_f32_16x16x32_bf16(al[m], bl[n], acc[m][n], 0, 0, 0);
            }
        __syncthreads();   // all ds_reads done before next tile overwrites LDS
    }

    // ---- epilogue: d = sqrt(max(xn+wn-2*dot,0)), store + argmin ----
    // C/D mapping (m89-verified): col = lane&15, row = (lane>>4)*4 + reg
    #pragma unroll
    for (int m = 0; m < 4; ++m) {
        #pragma unroll
        for (int reg = 0; reg < 4; ++reg) {
            const int rg = brow + wrow + m * 16 + q * 4 + reg;
            const float xv = xn[rg];
            unsigned long long best = 0xFFFFFFFFFFFFFFFFULL;
            #pragma unroll
            for (int n = 0; n < 4; ++n) {
                const int cg = bcol + wcol + n * 16 + s;
                float d2 = xv + wn[cg] - 2.0f * acc[m][n][reg];
                d2 = fmaxf(d2, 0.0f);
                float d = sqrtf(d2);
                out[(size_t)rg * NW + cg] = d;
                unsigned long long p =
                    ((unsigned long long)__float_as_uint(d) << 32) | (unsigned)cg;
                if (p < best) best = p;
            }
            #pragma unroll
            for (int o = 8; o; o >>= 1) {
                unsigned long long ob = __shfl_xor(best, o, 64);
                if (ob < best) best = ob;
            }
            if (s == 0) atomicMin(&bmu[rg], best);
        }
    }
}

// ---------------- fallback f32 path (round-1, known-passing) ----------------
#define BK  32
#define LDK 36

__global__ __launch_bounds__(256) void som_prep(const float* __restrict__ x,
                                                const float* __restrict__ w,
                                                float* __restrict__ xn,
                                                float* __restrict__ wn,
                                                unsigned long long* __restrict__ bmu) {
    const int wave = threadIdx.x >> 6;
    const int lane = threadIdx.x & 63;
    const int row  = blockIdx.x * 4 + wave;
    const float* src = (row < BATCH) ? (x + (size_t)row * FEAT)
                                     : (w + (size_t)(row - BATCH) * FEAT);
    float4 v = ((const float4*)src)[lane];
    float s = v.x * v.x + v.y * v.y + v.z * v.z + v.w * v.w;
    #pragma unroll
    for (int off = 32; off >= 1; off >>= 1) s += __shfl_xor(s, off, 64);
    if (lane == 0) {
        if (row < BATCH) { xn[row] = s; bmu[row] = 0xFFFFFFFFFFFFFFFFULL; }
        else             { wn[row - BATCH] = s; }
    }
}

__global__ __launch_bounds__(256) void som_f32main(const float* __restrict__ x,
                                                   const float* __restrict__ w,
                                                   const float* __restrict__ xn,
                                                   const float* __restrict__ wn,
                                                   float* __restrict__ out,
                                                   unsigned long long* __restrict__ bmu) {
    __shared__ float xs[BM][LDK];
    __shared__ float wsh[BN][LDK];
    const int t  = threadIdx.x;
    const int tx = t & 15;
    const int ty = t >> 4;
    const int brow = blockIdx.y * BM;
    const int bcol = blockIdx.x * BN;
    float acc[8][8];
    #pragma unroll
    for (int i = 0; i < 8; ++i)
        #pragma unroll
        for (int j = 0; j < 8; ++j) acc[i][j] = 0.0f;
    for (int k0 = 0; k0 < FEAT; k0 += BK) {
        #pragma unroll
        for (int r = 0; r < 4; ++r) {
            const int flat = (t + r * 256) * 4;
            const int row  = flat >> 5;
            const int col  = flat & 31;
            float4 xv = *(const float4*)&x[(size_t)(brow + row) * FEAT + k0 + col];
            float4 wv = *(const float4*)&w[(size_t)(bcol + row) * FEAT + k0 + col];
            *(float4*)&xs[row][col]  = xv;
            *(float4*)&wsh[row][col] = wv;
        }
        __syncthreads();
        #pragma unroll
        for (int kq = 0; kq < BK / 4; ++kq) {
            float4 a[8], b[8];
            #pragma unroll
            for (int i = 0; i < 8; ++i) a[i] = *(const float4*)&xs[ty + 16 * i][kq * 4];
            #pragma unroll
            for (int j = 0; j < 8; ++j) b[j] = *(const float4*)&wsh[tx + 16 * j][kq * 4];
            #pragma unroll
            for (int i = 0; i < 8; ++i)
                #pragma unroll
                for (int j = 0; j < 8; ++j) {
                    acc[i][j] += a[i].x * b[j].x;
                    acc[i][j] += a[i].y * b[j].y;
                    acc[i][j] += a[i].z * b[j].z;
                    acc[i][j] += a[i].w * b[j].w;
                }
        }
        __syncthreads();
    }
    #pragma unroll
    for (int i = 0; i < 8; ++i) {
        const int rg = brow + ty + 16 * i;
        const float xnv = xn[rg];
        unsigned long long best = 0xFFFFFFFFFFFFFFFFULL;
        #pragma unroll
        for (int j = 0; j < 8; ++j) {
            const int cg = bcol + tx + 16 * j;
            float d2 = xnv + wn[cg] - 2.0f * acc[i][j];
            d2 = fmaxf(d2, 0.0f);
            float d = sqrtf(d2);
            out[(size_t)rg * NW + cg] = d;
            unsigned long long p =
                ((unsigned long long)__float_as_uint(d) << 32) | (unsigned int)cg;
            if (p < best) best = p;
        }
        #pragma unroll
        for (int off = 8; off >= 1; off >>= 1) {
            unsigned long long o = __shfl_xor(best, off, 64);
            if (o < best) best = o;
        }
        if (tx == 0) atomicMin(&bmu[rg], best);
    }
}

__global__ __launch_bounds__(256) void som_bmu_write(const unsigned long long* __restrict__ bmu,
                                                     float* __restrict__ outb) {
    const int i = blockIdx.x * blockDim.x + threadIdx.x;
    if (i >= BATCH) return;
    const unsigned int idx = (unsigned int)(bmu[i] & 0xFFFFFFFFu);
    outb[(size_t)i * 2 + 0] = (float)(idx >> 7);
    outb[(size_t)i * 2 + 1] = (float)(idx & (SOMC - 1));
}

extern "C" void kernel_launch(void* const* d_in, const int* in_sizes, int n_in,
                              void* d_out, int out_size, void* d_ws, size_t ws_size,
                              hipStream_t stream) {
    const float* x = (const float*)d_in[0];
    const float* w = (const float*)d_in[1];
    float* out = (float*)d_out;

    float* xn = (float*)d_ws;
    float* wn = xn + BATCH;
    unsigned long long* bmu = (unsigned long long*)((char*)d_ws + 73728);
    float* outb = out + (size_t)BATCH * NW;

    if (ws_size >= WS_NEEDED) {
        unsigned short* xsp = (unsigned short*)((char*)d_ws + 90112);
        unsigned short* wsp = (unsigned short*)((char*)d_ws + 2187264);
        som_prep_split<<<(BATCH + NW) / 4, 256, 0, stream>>>(x, w, xn, wn, bmu, xsp, wsp);
        dim3 grid(NW / BN, BATCH / BM);   // 128 x 16
        som_mfma<<<grid, 256, 0, stream>>>(xsp, wsp, xn, wn, out, bmu);
    } else {
        som_prep<<<(BATCH + NW) / 4, 256, 0, stream>>>(x, w, xn, wn, bmu);
        dim3 grid(NW / BN, BATCH / BM);
        som_f32main<<<grid, 256, 0, stream>>>(x, w, xn, wn, out, bmu);
    }
    som_bmu_write<<<(BATCH + 255) / 256, 256, 0, stream>>>(bmu, outb);
}